// Round 6
// baseline (410.023 us; speedup 1.0000x reference)
//
#include <hip/hip_runtime.h>
#include <hip/hip_bf16.h>

#define NTOK 65536
#define DD 256
#define FF 1024
#define EE 8
#define BSTRIDE 12288
#define MTILE 128
#define NTILES (BSTRIDE / MTILE)   // 96

typedef short bh8 __attribute__((ext_vector_type(8)));
typedef float f16v __attribute__((ext_vector_type(16)));

__device__ __forceinline__ unsigned rotl32(unsigned v, int d) {
  return (v << d) | (v >> (32 - d));
}

// JAX threefry2x32, 20 rounds. key = jax.random.key(42) -> (0, 42).
// partitionable: counter for flat element j is (hi,lo)=(0,j); out = x0 ^ x1.
__device__ __forceinline__ unsigned jax_random_bits32(unsigned c0, unsigned c1) {
  const unsigned k0 = 0u, k1 = 42u;
  const unsigned k2 = 0x1BD11BDAu ^ k0 ^ k1;
  unsigned x0 = c0 + k0, x1 = c1 + k1;
#define TFR(r) { x0 += x1; x1 = rotl32(x1, (r)); x1 ^= x0; }
  TFR(13) TFR(15) TFR(26) TFR(6)
  x0 += k1; x1 += k2 + 1u;
  TFR(17) TFR(29) TFR(16) TFR(24)
  x0 += k2; x1 += k0 + 2u;
  TFR(13) TFR(15) TFR(26) TFR(6)
  x0 += k0; x1 += k1 + 3u;
  TFR(17) TFR(29) TFR(16) TFR(24)
  x0 += k1; x1 += k2 + 4u;
  TFR(13) TFR(15) TFR(26) TFR(6)
  x0 += k2; x1 += k0 + 5u;
#undef TFR
  return x0 ^ x1;
}

__device__ __forceinline__ ushort f2bf(float f) {
  union { float f; unsigned u; } c; c.f = f;
  unsigned r = c.u + 0x7fffu + ((c.u >> 16) & 1u);
  return (ushort)(r >> 16);
}

// ---------------- gate + route (+ optional x -> bf16 copy) ----------------
__global__ __launch_bounds__(1024) void gate_route3(
    const float* __restrict__ x, const float* __restrict__ gw,
    const float* __restrict__ gb, int* __restrict__ counts,
    int* __restrict__ buckets, ushort* __restrict__ xbf) {
  __shared__ float gwt[EE * DD];
  __shared__ int hist[EE], sbase[EE];
  __shared__ unsigned char chs[64];
  __shared__ short lps[64];

  const int tid = threadIdx.x;
  if (tid < EE) hist[tid] = 0;
  for (int i = tid; i < DD * EE; i += 1024) {
    const int d = i >> 3, e = i & 7;
    gwt[e * DD + d] = gw[i];
  }
  __syncthreads();

  const int lane = tid & 63;
  const int wave = tid >> 6;
  const int grp = lane >> 4;
  const int gl = lane & 15;
  const int slot = wave * 4 + grp;
  const int t = blockIdx.x * 64 + slot;

  float acc[EE] = {0.f, 0.f, 0.f, 0.f, 0.f, 0.f, 0.f, 0.f};
  const float* xr = x + (size_t)t * DD;
#pragma unroll
  for (int j = 0; j < 4; ++j) {
    const int d0 = j * 64 + gl * 4;
    const float4 xv = *reinterpret_cast<const float4*>(xr + d0);
    if (xbf != nullptr) {   // fused bf16 conversion of x (consumed by ffn_mfma3)
      ushort4 xb;
      xb.x = f2bf(xv.x); xb.y = f2bf(xv.y); xb.z = f2bf(xv.z); xb.w = f2bf(xv.w);
      *reinterpret_cast<ushort4*>(xbf + (size_t)t * DD + d0) = xb;
    }
#pragma unroll
    for (int e = 0; e < EE; ++e) {
      const float4 g = *reinterpret_cast<const float4*>(&gwt[e * DD + d0]);
      acc[e] = fmaf(xv.x, g.x, acc[e]);
      acc[e] = fmaf(xv.y, g.y, acc[e]);
      acc[e] = fmaf(xv.z, g.z, acc[e]);
      acc[e] = fmaf(xv.w, g.w, acc[e]);
    }
  }
#pragma unroll
  for (int off = 8; off >= 1; off >>= 1)
#pragma unroll
    for (int e = 0; e < EE; ++e) acc[e] += __shfl_xor(acc[e], off);

  const int e = gl & 7;
  float logit = 0.f;
#pragma unroll
  for (int q = 0; q < EE; ++q) logit = (e == q) ? acc[q] : logit;
  logit += gb[e];

  const unsigned bits = jax_random_bits32(0u, (unsigned)(t * EE + e));
  const float f = __uint_as_float((bits >> 9) | 0x3f800000u) - 1.0f;
  const float u = fmaxf(1.17549435e-38f, f);
  float val = -logf(-logf(u)) + logit;
  int idx = e;
#pragma unroll
  for (int off = 4; off > 0; off >>= 1) {
    const float ov = __shfl_xor(val, off);
    const int oi = __shfl_xor(idx, off);
    if (ov > val || (ov == val && oi < idx)) { val = ov; idx = oi; }
  }
  if (gl == 0) {
    const int lp = atomicAdd(&hist[idx], 1);
    chs[slot] = (unsigned char)idx;
    lps[slot] = (short)lp;
  }
  __syncthreads();
  if (tid < EE) sbase[tid] = atomicAdd(&counts[tid], hist[tid]);
  __syncthreads();
  if (tid < 64) {
    const int ee = chs[tid];
    const int p = sbase[ee] + lps[tid];
    if (p < BSTRIDE) buckets[ee * BSTRIDE + p] = blockIdx.x * 64 + tid;
  }
}

// ---------------- weight transpose + fp32->bf16: dst[e][c][r] = src[e][r][c] ----------------
__global__ __launch_bounds__(256) void transpose_cvt(
    const float* __restrict__ src, ushort* __restrict__ dst, int R, int C) {
  __shared__ float ts[64][65];
  const int e = blockIdx.z;
  const int r0 = blockIdx.y * 64, c0 = blockIdx.x * 64;
  const int tx = threadIdx.x, ty = threadIdx.y;
  const float* s = src + (size_t)e * R * C;
  ushort* d = dst + (size_t)e * R * C;
#pragma unroll
  for (int i = 0; i < 16; ++i)
    ts[ty * 16 + i][tx] = s[(size_t)(r0 + ty * 16 + i) * C + c0 + tx];
  __syncthreads();
#pragma unroll
  for (int i = 0; i < 16; ++i)
    d[(size_t)(c0 + ty * 16 + i) * R + r0 + tx] = f2bf(ts[tx][ty * 16 + i]);
}

// ---------------- MFMA FFN v3: 32x32x16, M=128, X in regs, H-only LDS ----------------
__global__ __launch_bounds__(512, 2) void ffn_mfma3(
    const ushort* __restrict__ xbf, const ushort* __restrict__ w1t,
    const float* __restrict__ b1, const ushort* __restrict__ w2t,
    const float* __restrict__ b2, const int* __restrict__ counts,
    const int* __restrict__ buckets, float* __restrict__ out) {
  const int e = blockIdx.x & 7;       // expert = id%8 -> pins expert weights per-XCD L2
  const int tile = blockIdx.x >> 3;
  const int cnt = min(counts[e], BSTRIDE);
  const int m0 = tile * MTILE;
  if (m0 >= cnt) return;

  __shared__ ushort Hp[2][MTILE * 64];  // 2 x 16 KB ping-pong
  __shared__ int toks[MTILE];

  const int tid = threadIdx.x;
  const int lane = tid & 63;
  const int wid = tid >> 6;
  const int l31 = lane & 31;
  const int h = lane >> 5;            // 0/1

  const int g = wid >> 2;             // GEMM1: f-group (2 x 32 within 64-chunk)
  const int j = wid & 3;              // GEMM1: m-block (4 x 32)
  const int mh = wid >> 2;            // GEMM2: m-half (2 x 64)
  const int dq = wid & 3;             // GEMM2: d-quarter (4 x 64)

  if (tid < MTILE) {
    const int i = m0 + tid;
    toks[tid] = buckets[e * BSTRIDE + (i < cnt ? i : cnt - 1)];
  }

  // X fragments for m-block j: 16 ksteps x 16B = 32 VGPR, loaded once.
  const int mx = m0 + j * 32 + l31;
  const int tokx = buckets[e * BSTRIDE + (mx < cnt ? mx : cnt - 1)];
  const ushort* xp = xbf + (size_t)tokx * DD + h * 8;
  bh8 xf[16];
#pragma unroll
  for (int ks = 0; ks < 16; ++ks)
    xf[ks] = *reinterpret_cast<const bh8*>(xp + ks * 16);

  const ushort* w1w = w1t + ((size_t)e * FF + g * 32 + l31) * DD + h * 8;
  const ushort* w2w = w2t + ((size_t)e * DD + dq * 64 + l31) * FF + h * 8;
  const int mrow = j * 32 + l31;
  const int hswz = (mrow & 7) << 4;

  bh8 af[16];
#pragma unroll
  for (int ks = 0; ks < 16; ++ks)
    af[ks] = *reinterpret_cast<const bh8*>(w1w + ks * 16);

  auto gemm1 = [&](int cc, int hb) {
    f16v hacc = {};
#pragma unroll
    for (int ks = 0; ks < 16; ++ks)
      hacc = __builtin_amdgcn_mfma_f32_32x32x16_bf16(af[ks], xf[ks], hacc, 0, 0, 0);
    char* hbase = reinterpret_cast<char*>(&Hp[hb][0]);
#pragma unroll
    for (int q = 0; q < 4; ++q) {
      const float4 b1v = *reinterpret_cast<const float4*>(
          b1 + e * FF + cc * 64 + g * 32 + q * 8 + 4 * h);
      ushort4 hv;
      hv.x = f2bf(fmaxf(hacc[q * 4 + 0] + b1v.x, 0.f));
      hv.y = f2bf(fmaxf(hacc[q * 4 + 1] + b1v.y, 0.f));
      hv.z = f2bf(fmaxf(hacc[q * 4 + 2] + b1v.z, 0.f));
      hv.w = f2bf(fmaxf(hacc[q * 4 + 3] + b1v.w, 0.f));
      const int byte = (mrow * 128 + (g * 32 + q * 8 + 4 * h) * 2) ^ hswz;
      *reinterpret_cast<ushort4*>(hbase + byte) = hv;
    }
  };

  // prologue: chunk 0 -> Hp[0], prefetch af(1)
  gemm1(0, 0);
#pragma unroll
  for (int ks = 0; ks < 16; ++ks)
    af[ks] = *reinterpret_cast<const bh8*>(w1w + (size_t)64 * DD + ks * 16);
  __syncthreads();

  f16v yacc[2][2] = {};

#pragma unroll 1
  for (int c = 0; c < 16; ++c) {
    // issue w2 B-frags for chunk c (latency hidden under GEMM1(c+1))
    bh8 b2f[2][4];
#pragma unroll
    for (int db = 0; db < 2; ++db)
#pragma unroll
      for (int ks = 0; ks < 4; ++ks)
        b2f[db][ks] = *reinterpret_cast<const bh8*>(
            w2w + (size_t)db * 32 * FF + c * 64 + ks * 16);

    if (c < 15) {
      gemm1(c + 1, (c + 1) & 1);   // writes the buffer GEMM2(c) is NOT reading
      if (c + 2 < 16) {
#pragma unroll
        for (int ks = 0; ks < 16; ++ks)
          af[ks] = *reinterpret_cast<const bh8*>(
              w1w + (size_t)(c + 2) * 64 * DD + ks * 16);
      }
    }

    const char* hbase = reinterpret_cast<const char*>(&Hp[c & 1][0]);
#pragma unroll
    for (int ks = 0; ks < 4; ++ks) {
      bh8 hfa[2];
#pragma unroll
      for (int mb = 0; mb < 2; ++mb) {
        const int m = mh * 64 + mb * 32 + l31;
        const int byte = (m * 128 + ks * 32 + h * 16) ^ ((m & 7) << 4);
        hfa[mb] = *reinterpret_cast<const bh8*>(hbase + byte);
      }
#pragma unroll
      for (int mb = 0; mb < 2; ++mb) {
        yacc[mb][0] = __builtin_amdgcn_mfma_f32_32x32x16_bf16(hfa[mb], b2f[0][ks], yacc[mb][0], 0, 0, 0);
        yacc[mb][1] = __builtin_amdgcn_mfma_f32_32x32x16_bf16(hfa[mb], b2f[1][ks], yacc[mb][1], 0, 0, 0);
      }
    }
    __syncthreads();
  }

  // epilogue: + b2, scatter. Lane: col d = dq*64 + db*32 + l31; 16 m-rows per acc.
  const float b2v0 = b2[e * DD + dq * 64 + l31];
  const float b2v1 = b2[e * DD + dq * 64 + 32 + l31];
#pragma unroll
  for (int mb = 0; mb < 2; ++mb) {
#pragma unroll
    for (int r = 0; r < 16; ++r) {
      const int m = mh * 64 + mb * 32 + (r & 3) + 8 * (r >> 2) + 4 * h;
      if (m0 + m < cnt) {
        const size_t ro = (size_t)toks[m] * DD + dq * 64 + l31;
        out[ro] = yacc[mb][0][r] + b2v0;
        out[ro + 32] = yacc[mb][1][r] + b2v1;
      }
    }
  }
}

// ---------------- fallback fp32 FFN (proven in round 1) ----------------
__global__ __launch_bounds__(512) void ffn_fp32(
    const float* __restrict__ x, const float* __restrict__ w1,
    const float* __restrict__ b1, const float* __restrict__ w2,
    const float* __restrict__ b2, const int* __restrict__ counts,
    const int* __restrict__ buckets, float* __restrict__ out, int bstride) {
  const int e = blockIdx.y;
  const int cnt = min(counts[e], bstride);
  const int m0 = blockIdx.x * 64;
  if (m0 >= cnt) return;

  __shared__ float Xt[DD][64];
  __shared__ float Ht[64][64];
  __shared__ int toks[64];

  const int tid = threadIdx.x;
  if (tid < 64) {
    const int i = m0 + tid;
    toks[tid] = buckets[e * bstride + (i < cnt ? i : cnt - 1)];
  }
  __syncthreads();

  for (int idx = tid; idx < 64 * (DD / 4); idx += 512) {
    const int r = idx >> 6;
    const int c4 = idx & 63;
    const float4 v = *reinterpret_cast<const float4*>(x + (size_t)toks[r] * DD + c4 * 4);
    Xt[c4 * 4 + 0][r] = v.x;
    Xt[c4 * 4 + 1][r] = v.y;
    Xt[c4 * 4 + 2][r] = v.z;
    Xt[c4 * 4 + 3][r] = v.w;
  }
  __syncthreads();

  const int fg = tid & 15;
  const int mg = tid >> 4;
  const int dc = tid & 63;
  const int mgrp = tid >> 6;

  float yacc[8][4];
#pragma unroll
  for (int i = 0; i < 8; ++i)
#pragma unroll
    for (int jj = 0; jj < 4; ++jj) yacc[i][jj] = 0.f;

  for (int fc0 = 0; fc0 < FF; fc0 += 64) {
    float hacc[2][4];
#pragma unroll
    for (int i = 0; i < 2; ++i)
#pragma unroll
      for (int jj = 0; jj < 4; ++jj) hacc[i][jj] = 0.f;

    const float* w1p = w1 + (size_t)e * DD * FF + fc0 + fg * 4;
    for (int d = 0; d < DD; ++d) {
      const float4 w = *reinterpret_cast<const float4*>(w1p + (size_t)d * FF);
      const float2 xv = *reinterpret_cast<const float2*>(&Xt[d][mg * 2]);
      const float ws[4] = {w.x, w.y, w.z, w.w};
      const float xl[2] = {xv.x, xv.y};
#pragma unroll
      for (int i = 0; i < 2; ++i)
#pragma unroll
        for (int jj = 0; jj < 4; ++jj)
          hacc[i][jj] = fmaf(xl[i], ws[jj], hacc[i][jj]);
    }
#pragma unroll
    for (int jj = 0; jj < 4; ++jj) {
      const float bb = b1[e * FF + fc0 + fg * 4 + jj];
      Ht[fg * 4 + jj][mg * 2 + 0] = fmaxf(hacc[0][jj] + bb, 0.f);
      Ht[fg * 4 + jj][mg * 2 + 1] = fmaxf(hacc[1][jj] + bb, 0.f);
    }
    __syncthreads();

    const float* w2p = w2 + (size_t)e * FF * DD + (size_t)fc0 * DD + dc * 4;
    for (int f = 0; f < 64; ++f) {
      const float4 w = *reinterpret_cast<const float4*>(w2p + (size_t)f * DD);
      const float4 h0 = *reinterpret_cast<const float4*>(&Ht[f][mgrp * 8]);
      const float4 h1 = *reinterpret_cast<const float4*>(&Ht[f][mgrp * 8 + 4]);
      const float hs[8] = {h0.x, h0.y, h0.z, h0.w, h1.x, h1.y, h1.z, h1.w};
      const float ws[4] = {w.x, w.y, w.z, w.w};
#pragma unroll
      for (int i = 0; i < 8; ++i)
#pragma unroll
        for (int jj = 0; jj < 4; ++jj)
          yacc[i][jj] = fmaf(hs[i], ws[jj], yacc[i][jj]);
    }
    __syncthreads();
  }

#pragma unroll
  for (int i = 0; i < 8; ++i) {
    const int r = mgrp * 8 + i;
    if (m0 + r < cnt) {
      float4 o;
      o.x = yacc[i][0] + b2[e * DD + dc * 4 + 0];
      o.y = yacc[i][1] + b2[e * DD + dc * 4 + 1];
      o.z = yacc[i][2] + b2[e * DD + dc * 4 + 2];
      o.w = yacc[i][3] + b2[e * DD + dc * 4 + 3];
      *reinterpret_cast<float4*>(out + (size_t)toks[r] * DD + dc * 4) = o;
    }
  }
}

extern "C" void kernel_launch(void* const* d_in, const int* in_sizes, int n_in,
                              void* d_out, int out_size, void* d_ws, size_t ws_size,
                              hipStream_t stream) {
  const float* x  = (const float*)d_in[0];
  const float* gw = (const float*)d_in[1];
  const float* gb = (const float*)d_in[2];
  const float* w1 = (const float*)d_in[3];
  const float* b1 = (const float*)d_in[4];
  const float* w2 = (const float*)d_in[5];
  const float* b2 = (const float*)d_in[6];
  float* out = (float*)d_out;

  // ws layout: counts @0 (4KB) | buckets @4K (384KB) | w1t @512K (4MB) |
  //            w2t @512K+4M (4MB) | xbf @512K+8M (32MB)
  int* counts = (int*)d_ws;
  int* buckets = (int*)((char*)d_ws + 4096);
  ushort* w1t = (ushort*)((char*)d_ws + 524288);
  ushort* w2t = (ushort*)((char*)d_ws + 524288 + 4194304);
  ushort* xbf = (ushort*)((char*)d_ws + 524288 + 2ull * 4194304);
  const size_t need = 524288 + 2ull * 4194304 + (size_t)NTOK * DD * 2;

  hipMemsetAsync(d_ws, 0, 4096, stream);

  if (ws_size >= need) {
    hipLaunchKernelGGL(gate_route3, dim3(NTOK / 64), dim3(1024), 0, stream,
                       x, gw, gb, counts, buckets, xbf);
    // w1 [e][256][1024] -> w1t [e][1024][256] ; w2 [e][1024][256] -> w2t [e][256][1024]
    hipLaunchKernelGGL(transpose_cvt, dim3(FF / 64, DD / 64, EE), dim3(64, 4), 0, stream,
                       w1, w1t, DD, FF);
    hipLaunchKernelGGL(transpose_cvt, dim3(DD / 64, FF / 64, EE), dim3(64, 4), 0, stream,
                       w2, w2t, FF, DD);
    hipLaunchKernelGGL(ffn_mfma3, dim3(NTILES * EE), dim3(512), 0, stream,
                       xbf, w1t, b1, w2t, b2, counts, buckets, out);
  } else {
    hipLaunchKernelGGL(gate_route3, dim3(NTOK / 64), dim3(1024), 0, stream,
                       x, gw, gb, counts, buckets, (ushort*)nullptr);
    hipLaunchKernelGGL(ffn_fp32, dim3(NTOK / 64, EE), dim3(512), 0, stream,
                       x, w1, b1, w2, b2, counts, buckets, out, BSTRIDE);
  }
}

// Round 7
// 363.444 us; speedup vs baseline: 1.1282x; 1.1282x over previous
//
#include <hip/hip_runtime.h>
#include <hip/hip_bf16.h>

#define NTOK 65536
#define DD 256
#define FF 1024
#define EE 8
#define BSTRIDE 12288
#define MTILE 128
#define NTILES (BSTRIDE / MTILE)   // 96

typedef short bh8 __attribute__((ext_vector_type(8)));
typedef float f16v __attribute__((ext_vector_type(16)));

__device__ __forceinline__ unsigned rotl32(unsigned v, int d) {
  return (v << d) | (v >> (32 - d));
}

// JAX threefry2x32, 20 rounds. key = jax.random.key(42) -> (0, 42).
// partitionable: counter for flat element j is (hi,lo)=(0,j); out = x0 ^ x1.
__device__ __forceinline__ unsigned jax_random_bits32(unsigned c0, unsigned c1) {
  const unsigned k0 = 0u, k1 = 42u;
  const unsigned k2 = 0x1BD11BDAu ^ k0 ^ k1;
  unsigned x0 = c0 + k0, x1 = c1 + k1;
#define TFR(r) { x0 += x1; x1 = rotl32(x1, (r)); x1 ^= x0; }
  TFR(13) TFR(15) TFR(26) TFR(6)
  x0 += k1; x1 += k2 + 1u;
  TFR(17) TFR(29) TFR(16) TFR(24)
  x0 += k2; x1 += k0 + 2u;
  TFR(13) TFR(15) TFR(26) TFR(6)
  x0 += k0; x1 += k1 + 3u;
  TFR(17) TFR(29) TFR(16) TFR(24)
  x0 += k1; x1 += k2 + 4u;
  TFR(13) TFR(15) TFR(26) TFR(6)
  x0 += k2; x1 += k0 + 5u;
#undef TFR
  return x0 ^ x1;
}

__device__ __forceinline__ ushort f2bf(float f) {
  union { float f; unsigned u; } c; c.f = f;
  unsigned r = c.u + 0x7fffu + ((c.u >> 16) & 1u);
  return (ushort)(r >> 16);
}

// ---------------- gate + route (+ optional x -> bf16 copy) ----------------
__global__ __launch_bounds__(1024) void gate_route3(
    const float* __restrict__ x, const float* __restrict__ gw,
    const float* __restrict__ gb, int* __restrict__ counts,
    int* __restrict__ buckets, ushort* __restrict__ xbf) {
  __shared__ float gwt[EE * DD];
  __shared__ int hist[EE], sbase[EE];
  __shared__ unsigned char chs[64];
  __shared__ short lps[64];

  const int tid = threadIdx.x;
  if (tid < EE) hist[tid] = 0;
  for (int i = tid; i < DD * EE; i += 1024) {
    const int d = i >> 3, e = i & 7;
    gwt[e * DD + d] = gw[i];
  }
  __syncthreads();

  const int lane = tid & 63;
  const int wave = tid >> 6;
  const int grp = lane >> 4;
  const int gl = lane & 15;
  const int slot = wave * 4 + grp;
  const int t = blockIdx.x * 64 + slot;

  float acc[EE] = {0.f, 0.f, 0.f, 0.f, 0.f, 0.f, 0.f, 0.f};
  const float* xr = x + (size_t)t * DD;
#pragma unroll
  for (int j = 0; j < 4; ++j) {
    const int d0 = j * 64 + gl * 4;
    const float4 xv = *reinterpret_cast<const float4*>(xr + d0);
    if (xbf != nullptr) {   // fused bf16 conversion of x (consumed by ffn_mfma4)
      ushort4 xb;
      xb.x = f2bf(xv.x); xb.y = f2bf(xv.y); xb.z = f2bf(xv.z); xb.w = f2bf(xv.w);
      *reinterpret_cast<ushort4*>(xbf + (size_t)t * DD + d0) = xb;
    }
#pragma unroll
    for (int e = 0; e < EE; ++e) {
      const float4 g = *reinterpret_cast<const float4*>(&gwt[e * DD + d0]);
      acc[e] = fmaf(xv.x, g.x, acc[e]);
      acc[e] = fmaf(xv.y, g.y, acc[e]);
      acc[e] = fmaf(xv.z, g.z, acc[e]);
      acc[e] = fmaf(xv.w, g.w, acc[e]);
    }
  }
#pragma unroll
  for (int off = 8; off >= 1; off >>= 1)
#pragma unroll
    for (int e = 0; e < EE; ++e) acc[e] += __shfl_xor(acc[e], off);

  const int e = gl & 7;
  float logit = 0.f;
#pragma unroll
  for (int q = 0; q < EE; ++q) logit = (e == q) ? acc[q] : logit;
  logit += gb[e];

  const unsigned bits = jax_random_bits32(0u, (unsigned)(t * EE + e));
  const float f = __uint_as_float((bits >> 9) | 0x3f800000u) - 1.0f;
  const float u = fmaxf(1.17549435e-38f, f);
  float val = -logf(-logf(u)) + logit;
  int idx = e;
#pragma unroll
  for (int off = 4; off > 0; off >>= 1) {
    const float ov = __shfl_xor(val, off);
    const int oi = __shfl_xor(idx, off);
    if (ov > val || (ov == val && oi < idx)) { val = ov; idx = oi; }
  }
  if (gl == 0) {
    const int lp = atomicAdd(&hist[idx], 1);
    chs[slot] = (unsigned char)idx;
    lps[slot] = (short)lp;
  }
  __syncthreads();
  if (tid < EE) sbase[tid] = atomicAdd(&counts[tid], hist[tid]);
  __syncthreads();
  if (tid < 64) {
    const int ee = chs[tid];
    const int p = sbase[ee] + lps[tid];
    if (p < BSTRIDE) buckets[ee * BSTRIDE + p] = blockIdx.x * 64 + tid;
  }
}

// ---------------- weight transpose + fp32->bf16: dst[e][c][r] = src[e][r][c] ----------------
__global__ __launch_bounds__(256) void transpose_cvt(
    const float* __restrict__ src, ushort* __restrict__ dst, int R, int C) {
  __shared__ float ts[64][65];
  const int e = blockIdx.z;
  const int r0 = blockIdx.y * 64, c0 = blockIdx.x * 64;
  const int tx = threadIdx.x, ty = threadIdx.y;
  const float* s = src + (size_t)e * R * C;
  ushort* d = dst + (size_t)e * R * C;
#pragma unroll
  for (int i = 0; i < 16; ++i)
    ts[ty * 16 + i][tx] = s[(size_t)(r0 + ty * 16 + i) * C + c0 + tx];
  __syncthreads();
#pragma unroll
  for (int i = 0; i < 16; ++i)
    d[(size_t)(c0 + ty * 16 + i) * R + r0 + tx] = f2bf(ts[tx][ty * 16 + i]);
}

// ---------------- MFMA FFN v4: 32x32x16, M=128, X in regs, STREAMED weights ----------------
// Same verified algebra as v3 (absmax 0.0039) but weight fragments are loaded
// at their single point of use instead of pre-held in arrays -> no spill.
__global__ __launch_bounds__(512, 2) void ffn_mfma4(
    const ushort* __restrict__ xbf, const ushort* __restrict__ w1t,
    const float* __restrict__ b1, const ushort* __restrict__ w2t,
    const float* __restrict__ b2, const int* __restrict__ counts,
    const int* __restrict__ buckets, float* __restrict__ out) {
  const int e = blockIdx.x & 7;       // expert = id%8 -> pins expert weights per-XCD L2
  const int tile = blockIdx.x >> 3;
  const int cnt = min(counts[e], BSTRIDE);
  const int m0 = tile * MTILE;
  if (m0 >= cnt) return;

  __shared__ ushort Hp[2][MTILE * 64];  // 2 x 16 KB ping-pong
  __shared__ int toks[MTILE];

  const int tid = threadIdx.x;
  const int lane = tid & 63;
  const int wid = tid >> 6;
  const int l31 = lane & 31;
  const int h = lane >> 5;            // 0/1

  const int g = wid >> 2;             // GEMM1: f-group (2 x 32 within 64-chunk)
  const int j = wid & 3;              // GEMM1: m-block (4 x 32)
  const int mh = wid >> 2;            // GEMM2: m-half (2 x 64)
  const int dq = wid & 3;             // GEMM2: d-quarter (4 x 64)

  if (tid < MTILE) {
    const int i = m0 + tid;
    toks[tid] = buckets[e * BSTRIDE + (i < cnt ? i : cnt - 1)];
  }

  // X fragments for m-block j: 16 ksteps x 16B = 32 VGPR, loaded once, reused 16x.
  const int mx = m0 + j * 32 + l31;
  const int tokx = buckets[e * BSTRIDE + (mx < cnt ? mx : cnt - 1)];
  const ushort* xp = xbf + (size_t)tokx * DD + h * 8;
  bh8 xf[16];
#pragma unroll
  for (int ks = 0; ks < 16; ++ks)
    xf[ks] = *reinterpret_cast<const bh8*>(xp + ks * 16);

  const ushort* w1w = w1t + ((size_t)e * FF + g * 32 + l31) * DD + h * 8;
  const ushort* w2w = w2t + ((size_t)e * DD + dq * 64 + l31) * FF + h * 8;
  const int mrow = j * 32 + l31;
  const int hswz = (mrow & 7) << 4;

  // GEMM1 for chunk cc -> buffer hb; w1 fragments streamed from L2.
  auto gemm1 = [&](int cc, int hb) {
    const ushort* wp = w1w + (size_t)cc * 64 * DD;
    f16v hacc = {};
#pragma unroll
    for (int ks = 0; ks < 16; ++ks) {
      const bh8 a = *reinterpret_cast<const bh8*>(wp + ks * 16);
      hacc = __builtin_amdgcn_mfma_f32_32x32x16_bf16(a, xf[ks], hacc, 0, 0, 0);
    }
    char* hbase = reinterpret_cast<char*>(&Hp[hb][0]);
#pragma unroll
    for (int q = 0; q < 4; ++q) {
      const float4 b1v = *reinterpret_cast<const float4*>(
          b1 + e * FF + cc * 64 + g * 32 + q * 8 + 4 * h);
      ushort4 hv;
      hv.x = f2bf(fmaxf(hacc[q * 4 + 0] + b1v.x, 0.f));
      hv.y = f2bf(fmaxf(hacc[q * 4 + 1] + b1v.y, 0.f));
      hv.z = f2bf(fmaxf(hacc[q * 4 + 2] + b1v.z, 0.f));
      hv.w = f2bf(fmaxf(hacc[q * 4 + 3] + b1v.w, 0.f));
      const int byte = (mrow * 128 + (g * 32 + q * 8 + 4 * h) * 2) ^ hswz;
      *reinterpret_cast<ushort4*>(hbase + byte) = hv;
    }
  };

  // prologue: chunk 0 -> Hp[0]
  gemm1(0, 0);
  __syncthreads();

  f16v yacc[2][2] = {};

#pragma unroll 1
  for (int c = 0; c < 16; ++c) {
    if (c < 15)
      gemm1(c + 1, (c + 1) & 1);   // writes the buffer GEMM2(c) is NOT reading

    // GEMM2(c): H frags from Hp[c&1], w2 fragments streamed from L2.
    const char* hbase = reinterpret_cast<const char*>(&Hp[c & 1][0]);
#pragma unroll
    for (int ks = 0; ks < 4; ++ks) {
      bh8 hfa[2];
#pragma unroll
      for (int mb = 0; mb < 2; ++mb) {
        const int m = mh * 64 + mb * 32 + l31;
        const int byte = (m * 128 + ks * 32 + h * 16) ^ ((m & 7) << 4);
        hfa[mb] = *reinterpret_cast<const bh8*>(hbase + byte);
      }
      const bh8 bf0 = *reinterpret_cast<const bh8*>(w2w + c * 64 + ks * 16);
      const bh8 bf1 = *reinterpret_cast<const bh8*>(w2w + (size_t)32 * FF + c * 64 + ks * 16);
      yacc[0][0] = __builtin_amdgcn_mfma_f32_32x32x16_bf16(hfa[0], bf0, yacc[0][0], 0, 0, 0);
      yacc[0][1] = __builtin_amdgcn_mfma_f32_32x32x16_bf16(hfa[0], bf1, yacc[0][1], 0, 0, 0);
      yacc[1][0] = __builtin_amdgcn_mfma_f32_32x32x16_bf16(hfa[1], bf0, yacc[1][0], 0, 0, 0);
      yacc[1][1] = __builtin_amdgcn_mfma_f32_32x32x16_bf16(hfa[1], bf1, yacc[1][1], 0, 0, 0);
    }
    __syncthreads();
  }

  // epilogue: + b2, scatter. Lane: col d = dq*64 + db*32 + l31; 16 m-rows per acc.
  const float b2v0 = b2[e * DD + dq * 64 + l31];
  const float b2v1 = b2[e * DD + dq * 64 + 32 + l31];
#pragma unroll
  for (int mb = 0; mb < 2; ++mb) {
#pragma unroll
    for (int r = 0; r < 16; ++r) {
      const int m = mh * 64 + mb * 32 + (r & 3) + 8 * (r >> 2) + 4 * h;
      if (m0 + m < cnt) {
        const size_t ro = (size_t)toks[m] * DD + dq * 64 + l31;
        out[ro] = yacc[mb][0][r] + b2v0;
        out[ro + 32] = yacc[mb][1][r] + b2v1;
      }
    }
  }
}

// ---------------- fallback fp32 FFN (proven in round 1) ----------------
__global__ __launch_bounds__(512) void ffn_fp32(
    const float* __restrict__ x, const float* __restrict__ w1,
    const float* __restrict__ b1, const float* __restrict__ w2,
    const float* __restrict__ b2, const int* __restrict__ counts,
    const int* __restrict__ buckets, float* __restrict__ out, int bstride) {
  const int e = blockIdx.y;
  const int cnt = min(counts[e], bstride);
  const int m0 = blockIdx.x * 64;
  if (m0 >= cnt) return;

  __shared__ float Xt[DD][64];
  __shared__ float Ht[64][64];
  __shared__ int toks[64];

  const int tid = threadIdx.x;
  if (tid < 64) {
    const int i = m0 + tid;
    toks[tid] = buckets[e * bstride + (i < cnt ? i : cnt - 1)];
  }
  __syncthreads();

  for (int idx = tid; idx < 64 * (DD / 4); idx += 512) {
    const int r = idx >> 6;
    const int c4 = idx & 63;
    const float4 v = *reinterpret_cast<const float4*>(x + (size_t)toks[r] * DD + c4 * 4);
    Xt[c4 * 4 + 0][r] = v.x;
    Xt[c4 * 4 + 1][r] = v.y;
    Xt[c4 * 4 + 2][r] = v.z;
    Xt[c4 * 4 + 3][r] = v.w;
  }
  __syncthreads();

  const int fg = tid & 15;
  const int mg = tid >> 4;
  const int dc = tid & 63;
  const int mgrp = tid >> 6;

  float yacc[8][4];
#pragma unroll
  for (int i = 0; i < 8; ++i)
#pragma unroll
    for (int jj = 0; jj < 4; ++jj) yacc[i][jj] = 0.f;

  for (int fc0 = 0; fc0 < FF; fc0 += 64) {
    float hacc[2][4];
#pragma unroll
    for (int i = 0; i < 2; ++i)
#pragma unroll
      for (int jj = 0; jj < 4; ++jj) hacc[i][jj] = 0.f;

    const float* w1p = w1 + (size_t)e * DD * FF + fc0 + fg * 4;
    for (int d = 0; d < DD; ++d) {
      const float4 w = *reinterpret_cast<const float4*>(w1p + (size_t)d * FF);
      const float2 xv = *reinterpret_cast<const float2*>(&Xt[d][mg * 2]);
      const float ws[4] = {w.x, w.y, w.z, w.w};
      const float xl[2] = {xv.x, xv.y};
#pragma unroll
      for (int i = 0; i < 2; ++i)
#pragma unroll
        for (int jj = 0; jj < 4; ++jj)
          hacc[i][jj] = fmaf(xl[i], ws[jj], hacc[i][jj]);
    }
#pragma unroll
    for (int jj = 0; jj < 4; ++jj) {
      const float bb = b1[e * FF + fc0 + fg * 4 + jj];
      Ht[fg * 4 + jj][mg * 2 + 0] = fmaxf(hacc[0][jj] + bb, 0.f);
      Ht[fg * 4 + jj][mg * 2 + 1] = fmaxf(hacc[1][jj] + bb, 0.f);
    }
    __syncthreads();

    const float* w2p = w2 + (size_t)e * FF * DD + (size_t)fc0 * DD + dc * 4;
    for (int f = 0; f < 64; ++f) {
      const float4 w = *reinterpret_cast<const float4*>(w2p + (size_t)f * DD);
      const float4 h0 = *reinterpret_cast<const float4*>(&Ht[f][mgrp * 8]);
      const float4 h1 = *reinterpret_cast<const float4*>(&Ht[f][mgrp * 8 + 4]);
      const float hs[8] = {h0.x, h0.y, h0.z, h0.w, h1.x, h1.y, h1.z, h1.w};
      const float ws[4] = {w.x, w.y, w.z, w.w};
#pragma unroll
      for (int i = 0; i < 8; ++i)
#pragma unroll
        for (int jj = 0; jj < 4; ++jj)
          yacc[i][jj] = fmaf(hs[i], ws[jj], yacc[i][jj]);
    }
    __syncthreads();
  }

#pragma unroll
  for (int i = 0; i < 8; ++i) {
    const int r = mgrp * 8 + i;
    if (m0 + r < cnt) {
      float4 o;
      o.x = yacc[i][0] + b2[e * DD + dc * 4 + 0];
      o.y = yacc[i][1] + b2[e * DD + dc * 4 + 1];
      o.z = yacc[i][2] + b2[e * DD + dc * 4 + 2];
      o.w = yacc[i][3] + b2[e * DD + dc * 4 + 3];
      *reinterpret_cast<float4*>(out + (size_t)toks[r] * DD + dc * 4) = o;
    }
  }
}

extern "C" void kernel_launch(void* const* d_in, const int* in_sizes, int n_in,
                              void* d_out, int out_size, void* d_ws, size_t ws_size,
                              hipStream_t stream) {
  const float* x  = (const float*)d_in[0];
  const float* gw = (const float*)d_in[1];
  const float* gb = (const float*)d_in[2];
  const float* w1 = (const float*)d_in[3];
  const float* b1 = (const float*)d_in[4];
  const float* w2 = (const float*)d_in[5];
  const float* b2 = (const float*)d_in[6];
  float* out = (float*)d_out;

  // ws layout: counts @0 (4KB) | buckets @4K (384KB) | w1t @512K (4MB) |
  //            w2t @512K+4M (4MB) | xbf @512K+8M (32MB)
  int* counts = (int*)d_ws;
  int* buckets = (int*)((char*)d_ws + 4096);
  ushort* w1t = (ushort*)((char*)d_ws + 524288);
  ushort* w2t = (ushort*)((char*)d_ws + 524288 + 4194304);
  ushort* xbf = (ushort*)((char*)d_ws + 524288 + 2ull * 4194304);
  const size_t need = 524288 + 2ull * 4194304 + (size_t)NTOK * DD * 2;

  hipMemsetAsync(d_ws, 0, 4096, stream);

  if (ws_size >= need) {
    hipLaunchKernelGGL(gate_route3, dim3(NTOK / 64), dim3(1024), 0, stream,
                       x, gw, gb, counts, buckets, xbf);
    // w1 [e][256][1024] -> w1t [e][1024][256] ; w2 [e][1024][256] -> w2t [e][256][1024]
    hipLaunchKernelGGL(transpose_cvt, dim3(FF / 64, DD / 64, EE), dim3(64, 4), 0, stream,
                       w1, w1t, DD, FF);
    hipLaunchKernelGGL(transpose_cvt, dim3(DD / 64, FF / 64, EE), dim3(64, 4), 0, stream,
                       w2, w2t, FF, DD);
    hipLaunchKernelGGL(ffn_mfma4, dim3(NTILES * EE), dim3(512), 0, stream,
                       xbf, w1t, b1, w2t, b2, counts, buckets, out);
  } else {
    hipLaunchKernelGGL(gate_route3, dim3(NTOK / 64), dim3(1024), 0, stream,
                       x, gw, gb, counts, buckets, (ushort*)nullptr);
    hipLaunchKernelGGL(ffn_fp32, dim3(NTOK / 64, EE), dim3(512), 0, stream,
                       x, w1, b1, w2, b2, counts, buckets, out, BSTRIDE);
  }
}

// Round 8
// 175.403 us; speedup vs baseline: 2.3376x; 2.0720x over previous
//
#include <hip/hip_runtime.h>
#include <hip/hip_bf16.h>

#define NTOK 65536
#define DD 256
#define FF 1024
#define EE 8
#define BSTRIDE 12288
#define MTILE 128
#define NTILES (BSTRIDE / MTILE)   // 96
#define CHUNK_US 16384             // 32KB chunk image in ushorts

typedef short bh8 __attribute__((ext_vector_type(8)));
typedef float f16v __attribute__((ext_vector_type(16)));

__device__ __forceinline__ unsigned rotl32(unsigned v, int d) {
  return (v << d) | (v >> (32 - d));
}

// JAX threefry2x32, 20 rounds. key = jax.random.key(42) -> (0, 42).
// partitionable: counter for flat element j is (hi,lo)=(0,j); out = x0 ^ x1.
__device__ __forceinline__ unsigned jax_random_bits32(unsigned c0, unsigned c1) {
  const unsigned k0 = 0u, k1 = 42u;
  const unsigned k2 = 0x1BD11BDAu ^ k0 ^ k1;
  unsigned x0 = c0 + k0, x1 = c1 + k1;
#define TFR(r) { x0 += x1; x1 = rotl32(x1, (r)); x1 ^= x0; }
  TFR(13) TFR(15) TFR(26) TFR(6)
  x0 += k1; x1 += k2 + 1u;
  TFR(17) TFR(29) TFR(16) TFR(24)
  x0 += k2; x1 += k0 + 2u;
  TFR(13) TFR(15) TFR(26) TFR(6)
  x0 += k0; x1 += k1 + 3u;
  TFR(17) TFR(29) TFR(16) TFR(24)
  x0 += k1; x1 += k2 + 4u;
  TFR(13) TFR(15) TFR(26) TFR(6)
  x0 += k2; x1 += k0 + 5u;
#undef TFR
  return x0 ^ x1;
}

__device__ __forceinline__ ushort f2bf(float f) {
  union { float f; unsigned u; } c; c.f = f;
  unsigned r = c.u + 0x7fffu + ((c.u >> 16) & 1u);
  return (ushort)(r >> 16);
}

// ---------------- gate + route (+ optional x -> bf16 copy) ----------------
__global__ __launch_bounds__(1024) void gate_route3(
    const float* __restrict__ x, const float* __restrict__ gw,
    const float* __restrict__ gb, int* __restrict__ counts,
    int* __restrict__ buckets, ushort* __restrict__ xbf) {
  __shared__ float gwt[EE * DD];
  __shared__ int hist[EE], sbase[EE];
  __shared__ unsigned char chs[64];
  __shared__ short lps[64];

  const int tid = threadIdx.x;
  if (tid < EE) hist[tid] = 0;
  for (int i = tid; i < DD * EE; i += 1024) {
    const int d = i >> 3, e = i & 7;
    gwt[e * DD + d] = gw[i];
  }
  __syncthreads();

  const int lane = tid & 63;
  const int wave = tid >> 6;
  const int grp = lane >> 4;
  const int gl = lane & 15;
  const int slot = wave * 4 + grp;
  const int t = blockIdx.x * 64 + slot;

  float acc[EE] = {0.f, 0.f, 0.f, 0.f, 0.f, 0.f, 0.f, 0.f};
  const float* xr = x + (size_t)t * DD;
#pragma unroll
  for (int j = 0; j < 4; ++j) {
    const int d0 = j * 64 + gl * 4;
    const float4 xv = *reinterpret_cast<const float4*>(xr + d0);
    if (xbf != nullptr) {   // fused bf16 conversion of x (consumed by ffn_mfma5)
      ushort4 xb;
      xb.x = f2bf(xv.x); xb.y = f2bf(xv.y); xb.z = f2bf(xv.z); xb.w = f2bf(xv.w);
      *reinterpret_cast<ushort4*>(xbf + (size_t)t * DD + d0) = xb;
    }
#pragma unroll
    for (int e = 0; e < EE; ++e) {
      const float4 g = *reinterpret_cast<const float4*>(&gwt[e * DD + d0]);
      acc[e] = fmaf(xv.x, g.x, acc[e]);
      acc[e] = fmaf(xv.y, g.y, acc[e]);
      acc[e] = fmaf(xv.z, g.z, acc[e]);
      acc[e] = fmaf(xv.w, g.w, acc[e]);
    }
  }
#pragma unroll
  for (int off = 8; off >= 1; off >>= 1)
#pragma unroll
    for (int e = 0; e < EE; ++e) acc[e] += __shfl_xor(acc[e], off);

  const int e = gl & 7;
  float logit = 0.f;
#pragma unroll
  for (int q = 0; q < EE; ++q) logit = (e == q) ? acc[q] : logit;
  logit += gb[e];

  const unsigned bits = jax_random_bits32(0u, (unsigned)(t * EE + e));
  const float f = __uint_as_float((bits >> 9) | 0x3f800000u) - 1.0f;
  const float u = fmaxf(1.17549435e-38f, f);
  float val = -logf(-logf(u)) + logit;
  int idx = e;
#pragma unroll
  for (int off = 4; off > 0; off >>= 1) {
    const float ov = __shfl_xor(val, off);
    const int oi = __shfl_xor(idx, off);
    if (ov > val || (ov == val && oi < idx)) { val = ov; idx = oi; }
  }
  if (gl == 0) {
    const int lp = atomicAdd(&hist[idx], 1);
    chs[slot] = (unsigned char)idx;
    lps[slot] = (short)lp;
  }
  __syncthreads();
  if (tid < EE) sbase[tid] = atomicAdd(&counts[tid], hist[tid]);
  __syncthreads();
  if (tid < 64) {
    const int ee = chs[tid];
    const int p = sbase[ee] + lps[tid];
    if (p < BSTRIDE) buckets[ee * BSTRIDE + p] = blockIdx.x * 64 + tid;
  }
}

// ---------------- weight prep: swizzled LDS-image layouts ----------------
// w1s[e][chunk][32KB]: for f-local fl, d: ushort @ byte (fl*512 + d*2) ^ ((fl&31)<<4)
__global__ __launch_bounds__(256) void prep_w1s(
    const float* __restrict__ w1, ushort* __restrict__ w1s) {
  __shared__ float ts[64][65];   // [d-local][f-local]
  const int e = blockIdx.z;
  const int f0 = blockIdx.x * 64, d0 = blockIdx.y * 64;
  const int tx = threadIdx.x, ty = threadIdx.y;
  const float* s = w1 + (size_t)e * DD * FF;
  char* dimg = (char*)(w1s + (size_t)e * 16 * CHUNK_US + blockIdx.x * CHUNK_US);
#pragma unroll
  for (int i = 0; i < 16; ++i)
    ts[ty * 16 + i][tx] = s[(size_t)(d0 + ty * 16 + i) * FF + f0 + tx];
  __syncthreads();
#pragma unroll
  for (int i = 0; i < 16; ++i) {
    const int fl = ty * 16 + i;
    const int byte = ((fl * 512 + (d0 + tx) * 2)) ^ ((fl & 31) << 4);
    *reinterpret_cast<ushort*>(dimg + byte) = f2bf(ts[tx][fl]);
  }
}

// w2s[e][chunk][32KB]: for d, f-local fl: ushort @ byte (d*128 + fl*2) ^ ((d&7)<<4)
__global__ __launch_bounds__(256) void prep_w2s(
    const float* __restrict__ w2, ushort* __restrict__ w2s) {
  __shared__ float ts[64][65];   // [f-local][d-local]
  const int e = blockIdx.z;
  const int d0 = blockIdx.x * 64, f0 = blockIdx.y * 64;
  const int tx = threadIdx.x, ty = threadIdx.y;
  const float* s = w2 + (size_t)e * FF * DD;
  char* dimg = (char*)(w2s + (size_t)e * 16 * CHUNK_US + blockIdx.y * CHUNK_US);
#pragma unroll
  for (int i = 0; i < 16; ++i)
    ts[ty * 16 + i][tx] = s[(size_t)(f0 + ty * 16 + i) * DD + d0 + tx];
  __syncthreads();
#pragma unroll
  for (int i = 0; i < 16; ++i) {
    const int d = d0 + ty * 16 + i;
    const int byte = ((d * 128 + tx * 2)) ^ ((d & 7) << 4);
    *reinterpret_cast<ushort*>(dimg + byte) = f2bf(ts[tx][ty * 16 + i]);
  }
}

// stage one 32KB chunk image: 8 waves x 4 issues x 64 lanes x 16B (linear LDS write)
__device__ __forceinline__ void stage32k(const ushort* g, ushort* l, int wid, int lane) {
  const ushort* gs = g + wid * 2048 + lane * 8;
  ushort* ls = l + wid * 2048;
#pragma unroll
  for (int i = 0; i < 4; ++i)
    __builtin_amdgcn_global_load_lds(
        (const __attribute__((address_space(1))) void*)(gs + i * 512),
        (__attribute__((address_space(3))) void*)(ls + i * 512), 16, 0, 0);
}

// ---------------- MFMA FFN v5: LDS-staged weights, X in regs ----------------
// Per chunk c (64 f):
//   GEMM1(c): A-frags from W1b (swizzled ds_read, conflict-free), B=xf regs -> H
//   mid barrier (drains w2 staging of c, H visible, W1b reads done)
//   issue stage_w1(c+1)   [overlaps GEMM2(c)]
//   GEMM2(c): A-frags from Hb, B-frags from W2b -> yacc
//   end barrier (drains w1 staging, W2b reads done)
//   issue stage_w2(c+1)   [overlaps GEMM1(c+1)]
__global__ __launch_bounds__(512, 2) void ffn_mfma5(
    const ushort* __restrict__ xbf, const ushort* __restrict__ w1s,
    const float* __restrict__ b1, const ushort* __restrict__ w2s,
    const float* __restrict__ b2, const int* __restrict__ counts,
    const int* __restrict__ buckets, float* __restrict__ out) {
  const int e = blockIdx.x & 7;       // expert = id%8 -> pins expert weights per-XCD L2
  const int tile = blockIdx.x >> 3;
  const int cnt = min(counts[e], BSTRIDE);
  const int m0 = tile * MTILE;
  if (m0 >= cnt) return;

  __shared__ ushort W1b[CHUNK_US];     // 32KB
  __shared__ ushort W2b[CHUNK_US];     // 32KB
  __shared__ ushort Hb[MTILE * 64];    // 16KB
  __shared__ int toks[MTILE];

  const int tid = threadIdx.x;
  const int lane = tid & 63;
  const int wid = tid >> 6;
  const int l31 = lane & 31;
  const int h = lane >> 5;            // 0/1

  const int g = wid >> 2;             // GEMM1: f-group (2 x 32 within 64-chunk)
  const int j = wid & 3;              // GEMM1: m-block (4 x 32)
  const int mh = wid >> 2;            // GEMM2: m-half (2 x 64)
  const int dq = wid & 3;             // GEMM2: d-quarter (4 x 64)

  if (tid < MTILE) {
    const int i = m0 + tid;
    toks[tid] = buckets[e * BSTRIDE + (i < cnt ? i : cnt - 1)];
  }

  const ushort* w1g = w1s + (size_t)e * 16 * CHUNK_US;
  const ushort* w2g = w2s + (size_t)e * 16 * CHUNK_US;

  // prologue staging: chunk 0 weights
  stage32k(w1g, W1b, wid, lane);
  stage32k(w2g, W2b, wid, lane);

  // X fragments for m-block j: 16 ksteps x 16B = 32 VGPR, loaded once, reused 16x.
  const int mx = m0 + j * 32 + l31;
  const int tokx = buckets[e * BSTRIDE + (mx < cnt ? mx : cnt - 1)];
  const ushort* xp = xbf + (size_t)tokx * DD + h * 8;
  bh8 xf[16];
#pragma unroll
  for (int ks = 0; ks < 16; ++ks)
    xf[ks] = *reinterpret_cast<const bh8*>(xp + ks * 16);

  const int fl = g * 32 + l31;        // GEMM1 A-frag row
  const int w1x = (fl & 31) << 4;     // full 5-bit XOR -> conflict-free
  const int mrow = j * 32 + l31;
  const int hswz = (mrow & 7) << 4;

  __syncthreads();   // prologue staging complete (compiler drains vmcnt)

  f16v yacc[2][2] = {};

#pragma unroll 1
  for (int c = 0; c < 16; ++c) {
    // ---- GEMM1(c): W1 frags from LDS (swizzled), X from regs ----
    {
      const char* wb = reinterpret_cast<const char*>(W1b);
      f16v hacc = {};
#pragma unroll
      for (int ks = 0; ks < 16; ++ks) {
        const int byte = (fl * 512 + ks * 32 + h * 16) ^ w1x;
        const bh8 a = *reinterpret_cast<const bh8*>(wb + byte);
        hacc = __builtin_amdgcn_mfma_f32_32x32x16_bf16(a, xf[ks], hacc, 0, 0, 0);
      }
      char* hbase = reinterpret_cast<char*>(Hb);
#pragma unroll
      for (int q = 0; q < 4; ++q) {
        const float4 b1v = *reinterpret_cast<const float4*>(
            b1 + e * FF + c * 64 + g * 32 + q * 8 + 4 * h);
        ushort4 hv;
        hv.x = f2bf(fmaxf(hacc[q * 4 + 0] + b1v.x, 0.f));
        hv.y = f2bf(fmaxf(hacc[q * 4 + 1] + b1v.y, 0.f));
        hv.z = f2bf(fmaxf(hacc[q * 4 + 2] + b1v.z, 0.f));
        hv.w = f2bf(fmaxf(hacc[q * 4 + 3] + b1v.w, 0.f));
        const int byte = (mrow * 128 + (g * 32 + q * 8 + 4 * h) * 2) ^ hswz;
        *reinterpret_cast<ushort4*>(hbase + byte) = hv;
      }
    }
    __syncthreads();   // MID: H visible; W1b reads done; w2(c) staging drained

    if (c < 15)
      stage32k(w1g + (size_t)(c + 1) * CHUNK_US, W1b, wid, lane);  // overlaps GEMM2(c)

    // ---- GEMM2(c): H frags + W2 frags from LDS ----
    {
      const char* hbase = reinterpret_cast<const char*>(Hb);
      const char* wb = reinterpret_cast<const char*>(W2b);
      const int d0 = dq * 64 + l31;
#pragma unroll
      for (int ks = 0; ks < 4; ++ks) {
        bh8 hfa[2];
#pragma unroll
        for (int mb = 0; mb < 2; ++mb) {
          const int m = mh * 64 + mb * 32 + l31;
          const int byte = (m * 128 + ks * 32 + h * 16) ^ ((m & 7) << 4);
          hfa[mb] = *reinterpret_cast<const bh8*>(hbase + byte);
        }
        const int b0 = (d0 * 128 + ks * 32 + h * 16) ^ ((d0 & 7) << 4);
        const int d1 = d0 + 32;
        const int b1y = (d1 * 128 + ks * 32 + h * 16) ^ ((d1 & 7) << 4);
        const bh8 bf0 = *reinterpret_cast<const bh8*>(wb + b0);
        const bh8 bf1 = *reinterpret_cast<const bh8*>(wb + b1y);
        yacc[0][0] = __builtin_amdgcn_mfma_f32_32x32x16_bf16(hfa[0], bf0, yacc[0][0], 0, 0, 0);
        yacc[0][1] = __builtin_amdgcn_mfma_f32_32x32x16_bf16(hfa[0], bf1, yacc[0][1], 0, 0, 0);
        yacc[1][0] = __builtin_amdgcn_mfma_f32_32x32x16_bf16(hfa[1], bf0, yacc[1][0], 0, 0, 0);
        yacc[1][1] = __builtin_amdgcn_mfma_f32_32x32x16_bf16(hfa[1], bf1, yacc[1][1], 0, 0, 0);
      }
    }
    __syncthreads();   // END: W2b reads done; w1(c+1) staging drained

    if (c < 15)
      stage32k(w2g + (size_t)(c + 1) * CHUNK_US, W2b, wid, lane);  // overlaps GEMM1(c+1)
  }

  // epilogue: + b2, scatter. Lane: col d = dq*64 + db*32 + l31; 16 m-rows per acc.
  const float b2v0 = b2[e * DD + dq * 64 + l31];
  const float b2v1 = b2[e * DD + dq * 64 + 32 + l31];
#pragma unroll
  for (int mb = 0; mb < 2; ++mb) {
#pragma unroll
    for (int r = 0; r < 16; ++r) {
      const int m = mh * 64 + mb * 32 + (r & 3) + 8 * (r >> 2) + 4 * h;
      if (m0 + m < cnt) {
        const size_t ro = (size_t)toks[m] * DD + dq * 64 + l31;
        out[ro] = yacc[mb][0][r] + b2v0;
        out[ro + 32] = yacc[mb][1][r] + b2v1;
      }
    }
  }
}

// ---------------- fallback fp32 FFN (proven in round 1) ----------------
__global__ __launch_bounds__(512) void ffn_fp32(
    const float* __restrict__ x, const float* __restrict__ w1,
    const float* __restrict__ b1, const float* __restrict__ w2,
    const float* __restrict__ b2, const int* __restrict__ counts,
    const int* __restrict__ buckets, float* __restrict__ out, int bstride) {
  const int e = blockIdx.y;
  const int cnt = min(counts[e], bstride);
  const int m0 = blockIdx.x * 64;
  if (m0 >= cnt) return;

  __shared__ float Xt[DD][64];
  __shared__ float Ht[64][64];
  __shared__ int toks[64];

  const int tid = threadIdx.x;
  if (tid < 64) {
    const int i = m0 + tid;
    toks[tid] = buckets[e * bstride + (i < cnt ? i : cnt - 1)];
  }
  __syncthreads();

  for (int idx = tid; idx < 64 * (DD / 4); idx += 512) {
    const int r = idx >> 6;
    const int c4 = idx & 63;
    const float4 v = *reinterpret_cast<const float4*>(x + (size_t)toks[r] * DD + c4 * 4);
    Xt[c4 * 4 + 0][r] = v.x;
    Xt[c4 * 4 + 1][r] = v.y;
    Xt[c4 * 4 + 2][r] = v.z;
    Xt[c4 * 4 + 3][r] = v.w;
  }
  __syncthreads();

  const int fg = tid & 15;
  const int mg = tid >> 4;
  const int dc = tid & 63;
  const int mgrp = tid >> 6;

  float yacc[8][4];
#pragma unroll
  for (int i = 0; i < 8; ++i)
#pragma unroll
    for (int jj = 0; jj < 4; ++jj) yacc[i][jj] = 0.f;

  for (int fc0 = 0; fc0 < FF; fc0 += 64) {
    float hacc[2][4];
#pragma unroll
    for (int i = 0; i < 2; ++i)
#pragma unroll
      for (int jj = 0; jj < 4; ++jj) hacc[i][jj] = 0.f;

    const float* w1p = w1 + (size_t)e * DD * FF + fc0 + fg * 4;
    for (int d = 0; d < DD; ++d) {
      const float4 w = *reinterpret_cast<const float4*>(w1p + (size_t)d * FF);
      const float2 xv = *reinterpret_cast<const float2*>(&Xt[d][mg * 2]);
      const float ws[4] = {w.x, w.y, w.z, w.w};
      const float xl[2] = {xv.x, xv.y};
#pragma unroll
      for (int i = 0; i < 2; ++i)
#pragma unroll
        for (int jj = 0; jj < 4; ++jj)
          hacc[i][jj] = fmaf(xl[i], ws[jj], hacc[i][jj]);
    }
#pragma unroll
    for (int jj = 0; jj < 4; ++jj) {
      const float bb = b1[e * FF + fc0 + fg * 4 + jj];
      Ht[fg * 4 + jj][mg * 2 + 0] = fmaxf(hacc[0][jj] + bb, 0.f);
      Ht[fg * 4 + jj][mg * 2 + 1] = fmaxf(hacc[1][jj] + bb, 0.f);
    }
    __syncthreads();

    const float* w2p = w2 + (size_t)e * FF * DD + (size_t)fc0 * DD + dc * 4;
    for (int f = 0; f < 64; ++f) {
      const float4 w = *reinterpret_cast<const float4*>(w2p + (size_t)f * DD);
      const float4 h0 = *reinterpret_cast<const float4*>(&Ht[f][mgrp * 8]);
      const float4 h1 = *reinterpret_cast<const float4*>(&Ht[f][mgrp * 8 + 4]);
      const float hs[8] = {h0.x, h0.y, h0.z, h0.w, h1.x, h1.y, h1.z, h1.w};
      const float ws[4] = {w.x, w.y, w.z, w.w};
#pragma unroll
      for (int i = 0; i < 8; ++i)
#pragma unroll
        for (int jj = 0; jj < 4; ++jj)
          yacc[i][jj] = fmaf(hs[i], ws[jj], yacc[i][jj]);
    }
    __syncthreads();
  }

#pragma unroll
  for (int i = 0; i < 8; ++i) {
    const int r = mgrp * 8 + i;
    if (m0 + r < cnt) {
      float4 o;
      o.x = yacc[i][0] + b2[e * DD + dc * 4 + 0];
      o.y = yacc[i][1] + b2[e * DD + dc * 4 + 1];
      o.z = yacc[i][2] + b2[e * DD + dc * 4 + 2];
      o.w = yacc[i][3] + b2[e * DD + dc * 4 + 3];
      *reinterpret_cast<float4*>(out + (size_t)toks[r] * DD + dc * 4) = o;
    }
  }
}

extern "C" void kernel_launch(void* const* d_in, const int* in_sizes, int n_in,
                              void* d_out, int out_size, void* d_ws, size_t ws_size,
                              hipStream_t stream) {
  const float* x  = (const float*)d_in[0];
  const float* gw = (const float*)d_in[1];
  const float* gb = (const float*)d_in[2];
  const float* w1 = (const float*)d_in[3];
  const float* b1 = (const float*)d_in[4];
  const float* w2 = (const float*)d_in[5];
  const float* b2 = (const float*)d_in[6];
  float* out = (float*)d_out;

  // ws layout: counts @0 (4KB) | buckets @4K (384KB) | w1s @512K (4MB) |
  //            w2s @512K+4M (4MB) | xbf @512K+8M (32MB)
  int* counts = (int*)d_ws;
  int* buckets = (int*)((char*)d_ws + 4096);
  ushort* w1s = (ushort*)((char*)d_ws + 524288);
  ushort* w2s = (ushort*)((char*)d_ws + 524288 + 4194304);
  ushort* xbf = (ushort*)((char*)d_ws + 524288 + 2ull * 4194304);
  const size_t need = 524288 + 2ull * 4194304 + (size_t)NTOK * DD * 2;

  hipMemsetAsync(d_ws, 0, 4096, stream);

  if (ws_size >= need) {
    hipLaunchKernelGGL(gate_route3, dim3(NTOK / 64), dim3(1024), 0, stream,
                       x, gw, gb, counts, buckets, xbf);
    hipLaunchKernelGGL(prep_w1s, dim3(FF / 64, DD / 64, EE), dim3(64, 4), 0, stream,
                       w1, w1s);
    hipLaunchKernelGGL(prep_w2s, dim3(DD / 64, FF / 64, EE), dim3(64, 4), 0, stream,
                       w2, w2s);
    hipLaunchKernelGGL(ffn_mfma5, dim3(NTILES * EE), dim3(512), 0, stream,
                       xbf, w1s, b1, w2s, b2, counts, buckets, out);
  } else {
    hipLaunchKernelGGL(gate_route3, dim3(NTOK / 64), dim3(1024), 0, stream,
                       x, gw, gb, counts, buckets, (ushort*)nullptr);
    hipLaunchKernelGGL(ffn_fp32, dim3(NTOK / 64, EE), dim3(512), 0, stream,
                       x, w1, b1, w2, b2, counts, buckets, out, BSTRIDE);
  }
}